// Round 2
// baseline (149.887 us; speedup 1.0000x reference)
//
#include <hip/hip_runtime.h>
#include <hip/hip_bf16.h>

#define NROWS 8192
#define DIM   128
#define NT    64                  // NROWS / 128 tiles per dim
#define NBLK  (NT * (NT + 1) / 2) // 2080 triangle tiles
#define TOTAL_OUT 33550336u       // NROWS*(NROWS-1)/2

typedef short bf16x8 __attribute__((ext_vector_type(8)));   // 8 bf16 in 4 VGPRs
typedef float f32x4  __attribute__((ext_vector_type(4)));
typedef unsigned short u16x8 __attribute__((ext_vector_type(8)));
typedef f32x4 f32x4_a4 __attribute__((aligned(4)));         // unaligned-capable 16B store

// fp32 -> bf16 round-to-nearest-even (bit trick; inputs are finite gaussians)
static __device__ inline unsigned short f32_to_bf16(float f) {
    unsigned int u = __float_as_uint(f);
    u += 0x7FFFu + ((u >> 16) & 1u);
    return (unsigned short)(u >> 16);
}

// Block = one 16-row group. Converts to bf16 and writes FRAGMENT-MAJOR layout:
//   Xr entry index = ((g*4 + kk)*64 + lane)*8 bf16, lane = lrow + 16*kgrp
//   holds row g*16+lrow, bf16 cols [(kk*4+kgrp)*8 .. +8)
// so each MFMA operand fragment load in pdist is ONE contiguous 1KB wave load.
// Also computes per-row squared norms in fp32.
__global__ __launch_bounds__(256) void prep_kernel(const float* __restrict__ X,
                                                   unsigned short* __restrict__ Xr,
                                                   float* __restrict__ sq,
                                                   float* __restrict__ out) {
    __shared__ float sm[16][17];
    const int g = blockIdx.x;
    const int t = threadIdx.x;
    const int kk = t >> 6, lane = t & 63;
    const int lrow = lane & 15, kgrp = lane >> 4;

    const float* src = X + (size_t)(g * 16 + lrow) * DIM + (kk * 4 + kgrp) * 8;
    const float4 v0 = *reinterpret_cast<const float4*>(src);
    const float4 v1 = *reinterpret_cast<const float4*>(src + 4);

    u16x8 h;
    h[0] = f32_to_bf16(v0.x); h[1] = f32_to_bf16(v0.y);
    h[2] = f32_to_bf16(v0.z); h[3] = f32_to_bf16(v0.w);
    h[4] = f32_to_bf16(v1.x); h[5] = f32_to_bf16(v1.y);
    h[6] = f32_to_bf16(v1.z); h[7] = f32_to_bf16(v1.w);
    *reinterpret_cast<u16x8*>(Xr + ((size_t)(g * 4 + kk) * 64 + lane) * 8) = h;

    float p = v0.x * v0.x + v0.y * v0.y + v0.z * v0.z + v0.w * v0.w
            + v1.x * v1.x + v1.y * v1.y + v1.z * v1.z + v1.w * v1.w;
    sm[lrow][kk * 4 + kgrp] = p;
    __syncthreads();
    if (t < 16) {
        float s = 0.f;
        #pragma unroll
        for (int j = 0; j < 16; ++j) s += sm[t][j];
        sq[g * 16 + t] = s;
    }
    if (g == 0 && t == 0) out[TOTAL_OUT - 1] = 0.0f; // skipped pair (0,1) slot
}

// Triangle-tiled bf16 MFMA, NO LDS: operand fragments load straight from the
// L2-resident fragment-major buffer (1KB coalesced per wave-load). No barriers;
// waves independent. dist = sq[l]+sq[u]-2*dot -> out[u*(u-1)/2 - 1 + l].
__global__ __launch_bounds__(256, 3) void pdist_kernel(const unsigned short* __restrict__ Xr,
                                                       const float* __restrict__ sq,
                                                       float* __restrict__ out) {
    const int t  = threadIdx.x;
    const int bt = blockIdx.x;
    // decode triangle index: bt = bj*(bj+1)/2 + bi, bi <= bj
    int bj = (int)((sqrtf(8.0f * (float)bt + 1.0f) - 1.0f) * 0.5f);
    while ((bj + 1) * (bj + 2) / 2 <= bt) ++bj;
    while (bj * (bj + 1) / 2 > bt) --bj;
    const int bi = bt - bj * (bj + 1) / 2;

    const int wid  = t >> 6;
    const int lane = t & 63;
    const int wr   = wid >> 1;   // wave row (l dim), 0..1
    const int wc   = wid & 1;    // wave col (u dim), 0..1
    const int lrow = lane & 15;
    const int kgrp = lane >> 4;

    const bf16x8* __restrict__ F = reinterpret_cast<const bf16x8*>(Xr);
    const int gA = bi * 8 + wr * 4;  // 16-row group base for A (+m)
    const int gB = bj * 8 + wc * 4;  // 16-row group base for B (+n)

    f32x4 acc[4][4];
    const f32x4 fzero = {0.f, 0.f, 0.f, 0.f};
    #pragma unroll
    for (int m = 0; m < 4; ++m)
        #pragma unroll
        for (int n = 0; n < 4; ++n) acc[m][n] = fzero;

    bf16x8 a[2][4], b[2][4];
    #pragma unroll
    for (int m = 0; m < 4; ++m) {
        a[0][m] = F[((gA + m) * 4 + 0) * 64 + lane];
        b[0][m] = F[((gB + m) * 4 + 0) * 64 + lane];
    }
    #pragma unroll
    for (int kk = 0; kk < 4; ++kk) {          // fully unrolled: cur/nxt static
        const int cur = kk & 1, nxt = cur ^ 1;
        if (kk < 3) {
            #pragma unroll
            for (int m = 0; m < 4; ++m) {
                a[nxt][m] = F[((gA + m) * 4 + kk + 1) * 64 + lane];
                b[nxt][m] = F[((gB + m) * 4 + kk + 1) * 64 + lane];
            }
        }
        #pragma unroll
        for (int m = 0; m < 4; ++m)
            #pragma unroll
            for (int n = 0; n < 4; ++n)
                acc[m][n] = __builtin_amdgcn_mfma_f32_16x16x32_bf16(a[cur][m], b[cur][n], acc[m][n], 0, 0, 0);
    }

    // ---- epilogue: dist = sq[l] + sq[u] - 2*acc, scatter to triangle ----
    const int l0 = bi * 128 + wr * 64;
    const int u0 = bj * 128 + wc * 64;
    const int rj = kgrp * 4;     // C row offset within fragment: row = rj + j

    float squ[4];
    f32x4 sql[4];
    #pragma unroll
    for (int n = 0; n < 4; ++n) squ[n] = sq[u0 + n * 16 + lrow];
    #pragma unroll
    for (int m = 0; m < 4; ++m)
        sql[m] = *reinterpret_cast<const f32x4*>(sq + l0 + m * 16 + rj);

    if (bi != bj) {
        #pragma unroll
        for (int m = 0; m < 4; ++m) {
            #pragma unroll
            for (int n = 0; n < 4; ++n) {
                const int u = u0 + n * 16 + lrow;
                const size_t base = ((size_t)u * (u - 1)) / 2 - 1 + (size_t)(l0 + m * 16 + rj);
                f32x4 d;
                #pragma unroll
                for (int j = 0; j < 4; ++j) d[j] = sql[m][j] + squ[n] - 2.0f * acc[m][n][j];
                __builtin_nontemporal_store(d, reinterpret_cast<f32x4_a4*>(out + base));
            }
        }
    } else {
        // diagonal tile: mask l < u && u >= 2
        #pragma unroll
        for (int m = 0; m < 4; ++m) {
            #pragma unroll
            for (int n = 0; n < 4; ++n) {
                const int u = u0 + n * 16 + lrow;
                #pragma unroll
                for (int j = 0; j < 4; ++j) {
                    const int l = l0 + m * 16 + rj + j;
                    if (l < u && u >= 2) {
                        const float d = sql[m][j] + squ[n] - 2.0f * acc[m][n][j];
                        __builtin_nontemporal_store(d, out + ((size_t)u * (u - 1)) / 2 - 1 + l);
                    }
                }
            }
        }
    }
}

extern "C" void kernel_launch(void* const* d_in, const int* in_sizes, int n_in,
                              void* d_out, int out_size, void* d_ws, size_t ws_size,
                              hipStream_t stream) {
    const float* X = (const float*)d_in[0];
    float* out = (float*)d_out;
    unsigned short* Xr = (unsigned short*)d_ws;                       // 2 MB bf16, fragment-major
    float* sq = (float*)((char*)d_ws + (size_t)NROWS * DIM * 2);      // 32 KB norms

    prep_kernel<<<NROWS / 16, 256, 0, stream>>>(X, Xr, sq, out);
    pdist_kernel<<<NBLK, 256, 0, stream>>>(Xr, sq, out);
}

// Round 3
// 54.082 us; speedup vs baseline: 2.7715x; 2.7715x over previous
//
#include <hip/hip_runtime.h>
#include <hip/hip_bf16.h>

#define NROWS 8192
#define DIM   128
#define NT    64                  // NROWS / 128 tiles per dim
#define NBLK  (NT * (NT + 1) / 2) // 2080 triangle tiles
#define TOTAL_OUT 33550336u       // NROWS*(NROWS-1)/2

typedef short bf16x8 __attribute__((ext_vector_type(8)));   // 8 bf16 in 4 VGPRs
typedef float f32x4  __attribute__((ext_vector_type(4)));
typedef unsigned short u16x8 __attribute__((ext_vector_type(8)));

// fp32 -> bf16 round-to-nearest-even (bit trick; inputs are finite gaussians)
static __device__ inline unsigned short f32_to_bf16(float f) {
    unsigned int u = __float_as_uint(f);
    u += 0x7FFFu + ((u >> 16) & 1u);
    return (unsigned short)(u >> 16);
}

// Block = one 16-row group. Converts to bf16 and writes FRAGMENT-MAJOR layout:
//   Xr entry index = ((g*4 + kk)*64 + lane)*8 bf16, lane = lrow + 16*kgrp
//   holds row g*16+lrow, bf16 cols [(kk*4+kgrp)*8 .. +8)
// so each MFMA operand fragment load in pdist is ONE contiguous 1KB wave load.
// Also computes per-row squared norms in fp32.
__global__ __launch_bounds__(256) void prep_kernel(const float* __restrict__ X,
                                                   unsigned short* __restrict__ Xr,
                                                   float* __restrict__ sq,
                                                   float* __restrict__ out) {
    __shared__ float sm[16][17];
    const int g = blockIdx.x;
    const int t = threadIdx.x;
    const int kk = t >> 6, lane = t & 63;
    const int lrow = lane & 15, kgrp = lane >> 4;

    const float* src = X + (size_t)(g * 16 + lrow) * DIM + (kk * 4 + kgrp) * 8;
    const float4 v0 = *reinterpret_cast<const float4*>(src);
    const float4 v1 = *reinterpret_cast<const float4*>(src + 4);

    u16x8 h;
    h[0] = f32_to_bf16(v0.x); h[1] = f32_to_bf16(v0.y);
    h[2] = f32_to_bf16(v0.z); h[3] = f32_to_bf16(v0.w);
    h[4] = f32_to_bf16(v1.x); h[5] = f32_to_bf16(v1.y);
    h[6] = f32_to_bf16(v1.z); h[7] = f32_to_bf16(v1.w);
    *reinterpret_cast<u16x8*>(Xr + ((size_t)(g * 4 + kk) * 64 + lane) * 8) = h;

    float p = v0.x * v0.x + v0.y * v0.y + v0.z * v0.z + v0.w * v0.w
            + v1.x * v1.x + v1.y * v1.y + v1.z * v1.z + v1.w * v1.w;
    sm[lrow][kk * 4 + kgrp] = p;
    __syncthreads();
    if (t < 16) {
        float s = 0.f;
        #pragma unroll
        for (int j = 0; j < 16; ++j) s += sm[t][j];
        sq[g * 16 + t] = s;
    }
    if (g == 0 && t == 0) out[TOTAL_OUT - 1] = 0.0f; // skipped pair (0,1) slot
}

// Triangle-tiled bf16 MFMA, NO LDS: operand fragments load straight from the
// L2-resident fragment-major buffer (1KB coalesced per wave-load). No barriers;
// waves independent. dist = sq[l]+sq[u]-2*dot -> out[u*(u-1)/2 - 1 + l].
// Stores are PLAIN (L2 write-combining merges the unaligned 64B runs —
// nontemporal stores caused 1.7x write amplification in R2).
__global__ __launch_bounds__(256, 4) void pdist_kernel(const unsigned short* __restrict__ Xr,
                                                       const float* __restrict__ sq,
                                                       float* __restrict__ out) {
    const int t  = threadIdx.x;
    const int bt = blockIdx.x;
    // decode triangle index: bt = bj*(bj+1)/2 + bi, bi <= bj
    int bj = (int)((sqrtf(8.0f * (float)bt + 1.0f) - 1.0f) * 0.5f);
    while ((bj + 1) * (bj + 2) / 2 <= bt) ++bj;
    while (bj * (bj + 1) / 2 > bt) --bj;
    const int bi = bt - bj * (bj + 1) / 2;

    const int wid  = t >> 6;
    const int lane = t & 63;
    const int wr   = wid >> 1;   // wave row (l dim), 0..1
    const int wc   = wid & 1;    // wave col (u dim), 0..1
    const int lrow = lane & 15;
    const int kgrp = lane >> 4;

    const bf16x8* __restrict__ F = reinterpret_cast<const bf16x8*>(Xr);
    const int gA = bi * 8 + wr * 4;  // 16-row group base for A (+m)
    const int gB = bj * 8 + wc * 4;  // 16-row group base for B (+n)

    f32x4 acc[4][4];
    const f32x4 fzero = {0.f, 0.f, 0.f, 0.f};
    #pragma unroll
    for (int m = 0; m < 4; ++m)
        #pragma unroll
        for (int n = 0; n < 4; ++n) acc[m][n] = fzero;

    bf16x8 a[2][4], b[2][4];
    #pragma unroll
    for (int m = 0; m < 4; ++m) {
        a[0][m] = F[((gA + m) * 4 + 0) * 64 + lane];
        b[0][m] = F[((gB + m) * 4 + 0) * 64 + lane];
    }
    #pragma unroll
    for (int kk = 0; kk < 4; ++kk) {          // fully unrolled: cur/nxt static
        const int cur = kk & 1, nxt = cur ^ 1;
        if (kk < 3) {
            #pragma unroll
            for (int m = 0; m < 4; ++m) {
                a[nxt][m] = F[((gA + m) * 4 + kk + 1) * 64 + lane];
                b[nxt][m] = F[((gB + m) * 4 + kk + 1) * 64 + lane];
            }
        }
        #pragma unroll
        for (int m = 0; m < 4; ++m)
            #pragma unroll
            for (int n = 0; n < 4; ++n)
                acc[m][n] = __builtin_amdgcn_mfma_f32_16x16x32_bf16(a[cur][m], b[cur][n], acc[m][n], 0, 0, 0);
    }

    // ---- epilogue: dist = sq[l] + sq[u] - 2*acc, scatter to triangle ----
    const int l0 = bi * 128 + wr * 64;
    const int u0 = bj * 128 + wc * 64;
    const int rj = kgrp * 4;     // C row offset within fragment: row = rj + j

    float squ[4];
    f32x4 sql[4];
    #pragma unroll
    for (int n = 0; n < 4; ++n) squ[n] = sq[u0 + n * 16 + lrow];
    #pragma unroll
    for (int m = 0; m < 4; ++m)
        sql[m] = *reinterpret_cast<const f32x4*>(sq + l0 + m * 16 + rj);

    if (bi != bj) {
        #pragma unroll
        for (int m = 0; m < 4; ++m) {
            #pragma unroll
            for (int n = 0; n < 4; ++n) {
                const int u = u0 + n * 16 + lrow;
                const size_t base = ((size_t)u * (u - 1)) / 2 - 1 + (size_t)(l0 + m * 16 + rj);
                f32x4 d;
                #pragma unroll
                for (int j = 0; j < 4; ++j) d[j] = sql[m][j] + squ[n] - 2.0f * acc[m][n][j];
                __builtin_memcpy(out + base, &d, 16); // plain 16B store, 4B-aligned
            }
        }
    } else {
        // diagonal tile: mask l < u && u >= 2
        #pragma unroll
        for (int m = 0; m < 4; ++m) {
            #pragma unroll
            for (int n = 0; n < 4; ++n) {
                const int u = u0 + n * 16 + lrow;
                #pragma unroll
                for (int j = 0; j < 4; ++j) {
                    const int l = l0 + m * 16 + rj + j;
                    if (l < u && u >= 2) {
                        out[((size_t)u * (u - 1)) / 2 - 1 + l] = sql[m][j] + squ[n] - 2.0f * acc[m][n][j];
                    }
                }
            }
        }
    }
}

extern "C" void kernel_launch(void* const* d_in, const int* in_sizes, int n_in,
                              void* d_out, int out_size, void* d_ws, size_t ws_size,
                              hipStream_t stream) {
    const float* X = (const float*)d_in[0];
    float* out = (float*)d_out;
    unsigned short* Xr = (unsigned short*)d_ws;                       // 2 MB bf16, fragment-major
    float* sq = (float*)((char*)d_ws + (size_t)NROWS * DIM * 2);      // 32 KB norms

    prep_kernel<<<NROWS / 16, 256, 0, stream>>>(X, Xr, sq, out);
    pdist_kernel<<<NBLK, 256, 0, stream>>>(Xr, sq, out);
}